// Round 2
// baseline (293.106 us; speedup 1.0000x reference)
//
#include <hip/hip_runtime.h>
#include <cstddef>

// B=2048, C_IN=C_OUT=64, T=32, E=32768, K_HOPS=2, KSIZE=3
#define NB   2048
#define NE   32768
#define NTC  2048      // T*C floats per node
#define SLOPE_F 0.01f
#define EPS_F   1e-5f

// ---------------- edge-index width handling ----------------
// Reference dtype is int64; harness doc says integer -> int*. Detect at
// runtime: if int64 (LE), every odd 32-bit word is a high word == 0
// (values < 2048). If int32, odd words are random node ids.
__global__ __launch_bounds__(256)
void k_detect(const int* __restrict__ ei, int* __restrict__ mode)
{
    int k = blockIdx.x * 256 + threadIdx.x;
    if (ei[2 * k + 1] != 0) atomicOr(mode, 1);  // 1 => int32 layout
}

__device__ __forceinline__ int edge_src(const int* ei, int m, int e) {
    return m ? ei[e] : ei[2 * e];
}
__device__ __forceinline__ int edge_dst(const int* ei, int m, int e) {
    return m ? ei[NE + e] : ei[2 * (NE + e)];
}

__global__ __launch_bounds__(256)
void k_hist(const int* __restrict__ ei, const int* __restrict__ mode, int* __restrict__ hist)
{
    int e = blockIdx.x * 256 + threadIdx.x;
    int m = *mode;
    atomicAdd(&hist[edge_dst(ei, m, e)], 1);
}

// single block: CSR row-pointer scan + conv-weight transpose to wT4[i][o][4]
__global__ __launch_bounds__(256)
void k_scan(const int* __restrict__ hist, int* __restrict__ rowp, int* __restrict__ cur,
            const float* __restrict__ cw, float* __restrict__ wT4)
{
    __shared__ int part[256];
    int j = threadIdx.x;
    int loc[8]; int s = 0;
#pragma unroll
    for (int r = 0; r < 8; ++r) { loc[r] = hist[j * 8 + r]; s += loc[r]; }
    part[j] = s;
    __syncthreads();
    for (int off = 1; off < 256; off <<= 1) {
        int v = (j >= off) ? part[j - off] : 0;
        __syncthreads();
        part[j] += v;
        __syncthreads();
    }
    int excl = part[j] - s;
#pragma unroll
    for (int r = 0; r < 8; ++r) {
        rowp[j * 8 + r] = excl;
        cur [j * 8 + r] = excl;
        excl += loc[r];
    }
    if (j == 255) rowp[2048] = excl;  // == NE

    // weight transpose: wT4[((i*64)+o)*4 + k] = cw[o*192 + i*3 + k], k<3; pad k=3
    for (int r = 0; r < 64; ++r) {
        int idx = j + r * 256;            // 16384 total
        int i = idx >> 8, o = (idx >> 2) & 63, k = idx & 3;
        wT4[idx] = (k < 3) ? cw[o * 192 + i * 3 + k] : 0.f;
    }
}

__global__ __launch_bounds__(256)
void k_scat(const int* __restrict__ ei, const float* __restrict__ ew,
            const int* __restrict__ mode, int* __restrict__ cur,
            int* __restrict__ csrs, float* __restrict__ csrw)
{
    int e = blockIdx.x * 256 + threadIdx.x;
    int m = *mode;
    int d = edge_dst(ei, m, e);
    int pos = atomicAdd(&cur[d], 1);
    csrs[pos] = edge_src(ei, m, e);
    csrw[pos] = ew[e];
}

// ---------------- conv1d + leaky + LayerNorm + BN partials ----------------
// one block per batch element b; writes h_in[b][t][c], accumulates per-channel
// sum/sumsq into stats[0..127] via global fp32 atomics.
// Weights read from global wT4 (L1/L2-resident, 64KB) — NOT staged in LDS,
// keeping LDS ~9.8KB so ~5 blocks/CU reside (was 59KB -> 2 blocks/CU).
__global__ __launch_bounds__(256, 5)
void k_convln(const float* __restrict__ x, const float* __restrict__ wT4,
              const float* __restrict__ cb, const float* __restrict__ lg,
              const float* __restrict__ lb, float* __restrict__ h_in,
              float* __restrict__ stats)
{
    __shared__ __align__(16) float xp[64 * 36];   // xp[i][t+2]=x[i][t], zero pad
    __shared__ float red1[64], red2[64];
    __shared__ float wsum[8];
    __shared__ float bcast[2];

    const int b = blockIdx.x, j = threadIdx.x;
    const float* xb = x + (size_t)b * NTC;

#pragma unroll
    for (int r = 0; r < 8; ++r) {
        int idx = j + r * 256;                    // i = idx>>5, t = idx&31
        xp[(idx >> 5) * 36 + (idx & 31) + 2] = xb[idx];
    }
    {
        int i = j >> 2, s = j & 3;
        xp[i * 36 + ((s < 2) ? s : 32 + s)] = 0.f;  // zero pad slots 0,1,34,35
    }
    if (j < 64) { red1[j] = 0.f; red2[j] = 0.f; }
    __syncthreads();

    const int o = j & 63, g = j >> 6;
    const int t0 = g * 8;                         // channel o, t in [t0,t0+8)
    float acc[8];
    {
        float cbv = cb[o];
#pragma unroll
        for (int r = 0; r < 8; ++r) acc[r] = cbv;
    }
    const float4* wrow = (const float4*)wT4 + o;  // stride 64 float4s per i
    for (int i = 0; i < 64; ++i) {
        const float* xr = &xp[i * 36 + t0];       // wave-broadcast (same addr all lanes... per-group)
        float4 q0 = *(const float4*)(xr);
        float4 q1 = *(const float4*)(xr + 4);
        float2 q2 = *(const float2*)(xr + 8);
        float xw[10] = {q0.x,q0.y,q0.z,q0.w,q1.x,q1.y,q1.z,q1.w,q2.x,q2.y};
        float4 wv = __ldg(wrow + i * 64);         // coalesced 1KB/wave, L1/L2 hit
#pragma unroll
        for (int r = 0; r < 8; ++r)
            acc[r] += xw[r]*wv.x + xw[r+1]*wv.y + xw[r+2]*wv.z;
    }
    // leaky relu + local LN stats
    float s1 = 0.f, s2 = 0.f;
#pragma unroll
    for (int r = 0; r < 8; ++r) {
        float v = acc[r];
        v = (v >= 0.f) ? v : SLOPE_F * v;
        acc[r] = v;
        s1 += v; s2 += v * v;
    }
#pragma unroll
    for (int off = 32; off > 0; off >>= 1) {
        s1 += __shfl_down(s1, off, 64);
        s2 += __shfl_down(s2, off, 64);
    }
    if ((j & 63) == 0) { wsum[j >> 6] = s1; wsum[4 + (j >> 6)] = s2; }
    __syncthreads();
    if (j == 0) {
        float S1 = wsum[0] + wsum[1] + wsum[2] + wsum[3];
        float S2 = wsum[4] + wsum[5] + wsum[6] + wsum[7];
        float mu  = S1 * (1.f / 2048.f);
        float var = S2 * (1.f / 2048.f) - mu * mu;
        bcast[0] = mu;
        bcast[1] = rsqrtf(var + EPS_F);
    }
    __syncthreads();
    const float mu = bcast[0], rs = bcast[1];
    float hs1 = 0.f, hs2 = 0.f;
    float* hb = h_in + (size_t)b * NTC;
#pragma unroll
    for (int r = 0; r < 8; ++r) {
        int t = t0 + r;
        float h = (acc[r] - mu) * rs * lg[o * 32 + t] + lb[o * 32 + t];
        hb[t * 64 + o] = h;                        // coalesced: lanes span o
        hs1 += h; hs2 += h * h;
    }
    atomicAdd(&red1[o], hs1);
    atomicAdd(&red2[o], hs2);
    __syncthreads();
    if (j < 64)       atomicAdd(&stats[j], red1[j]);
    else if (j < 128) atomicAdd(&stats[j], red2[j - 64]);
}

// ---------------- BN stats -> scale/shift ----------------
__global__ void k_bnstats(float* __restrict__ stats, const float* __restrict__ bg,
                          const float* __restrict__ bb)
{
    int c = threadIdx.x;            // 64 threads
    const float inv_n = 1.f / 65536.f;
    float mu  = stats[c] * inv_n;
    float var = stats[64 + c] * inv_n - mu * mu;
    float rs  = rsqrtf(var + EPS_F);
    float sc  = bg[c] * rs;
    stats[128 + c] = sc;
    stats[192 + c] = bb[c] - mu * sc;
}

// ---------------- z = leaky(BN(h)); out = h + z@W0 + tag_b ----------------
__global__ __launch_bounds__(256, 4)
void k_zw0(const float* __restrict__ h_in, const float* __restrict__ stats,
           const float* __restrict__ tw, const float* __restrict__ tb,
           float* __restrict__ z, float* __restrict__ out)
{
    __shared__ float zl[32 * 65];
    __shared__ float hl[32 * 65];
    __shared__ float W[64 * 64];
    const int b = blockIdx.x, j = threadIdx.x;
#pragma unroll
    for (int r = 0; r < 16; ++r) { int idx = j + r * 256; W[idx] = tw[idx]; }
    const int c = j & 63;
    const float sc = stats[128 + c], sh = stats[192 + c];
    const float* hb = h_in + (size_t)b * NTC;
    float* zb = z + (size_t)b * NTC;
#pragma unroll
    for (int r = 0; r < 8; ++r) {
        int idx = j + r * 256;                    // idx = t*64 + c
        int t = idx >> 6;
        float h = hb[idx];
        float zv = h * sc + sh;
        zv = (zv >= 0.f) ? zv : SLOPE_F * zv;
        zb[idx] = zv;
        zl[t * 65 + c] = zv;
        hl[t * 65 + c] = h;
    }
    __syncthreads();
    const int t = j & 31, g0 = j >> 5;            // outputs (t, g0+8r)
    float accm[8];
#pragma unroll
    for (int r = 0; r < 8; ++r) {
        int gg = g0 + 8 * r;
        accm[r] = tb[gg] + hl[t * 65 + gg];       // residual + bias
    }
    for (int f = 0; f < 64; ++f) {
        float zv = zl[t * 65 + f];
#pragma unroll
        for (int r = 0; r < 8; ++r)
            accm[r] += zv * W[f * 64 + g0 + 8 * r];
    }
    float* ob = out + (size_t)b * NTC;            // out layout [b][c][t]
#pragma unroll
    for (int r = 0; r < 8; ++r)
        ob[(g0 + 8 * r) * 32 + t] = accm[r];      // coalesced: lanes span t
}

// ---------------- one propagation hop + fused matmul into out ----------------
__global__ __launch_bounds__(256, 4)
void k_hop(const float* __restrict__ p_in, const int* __restrict__ rowp,
           const int* __restrict__ csrs, const float* __restrict__ csrw,
           const float* __restrict__ tw, float* __restrict__ p_out,
           float* __restrict__ out)
{
    __shared__ float pl[32 * 65];
    __shared__ float W[64 * 64];
    const int d = blockIdx.x, j = threadIdx.x;
#pragma unroll
    for (int r = 0; r < 16; ++r) { int idx = j + r * 256; W[idx] = tw[idx]; }
    const int beg = rowp[d], end = rowp[d + 1];
    float4 a0 = make_float4(0.f,0.f,0.f,0.f), a1 = make_float4(0.f,0.f,0.f,0.f);
    for (int e = beg; e < end; ++e) {
        int s = csrs[e];
        float w = csrw[e];
        const float4* pb = (const float4*)(p_in + (size_t)s * NTC);
        float4 v0 = pb[j];                        // 1KB/wave, coalesced
        float4 v1 = pb[j + 256];
        a0.x += w * v0.x; a0.y += w * v0.y; a0.z += w * v0.z; a0.w += w * v0.w;
        a1.x += w * v1.x; a1.y += w * v1.y; a1.z += w * v1.z; a1.w += w * v1.w;
    }
    if (p_out) {
        float4* po = (float4*)(p_out + (size_t)d * NTC);
        po[j] = a0;
        po[j + 256] = a1;
    }
    {
        int idx = j * 4;
        int t = idx >> 6, c = idx & 63;
        float* q = &pl[t * 65 + c];
        q[0] = a0.x; q[1] = a0.y; q[2] = a0.z; q[3] = a0.w;
        idx = j * 4 + 1024; t = idx >> 6; c = idx & 63;
        q = &pl[t * 65 + c];
        q[0] = a1.x; q[1] = a1.y; q[2] = a1.z; q[3] = a1.w;
    }
    __syncthreads();
    const int t = j & 31, g0 = j >> 5;
    float accm[8];
#pragma unroll
    for (int r = 0; r < 8; ++r) accm[r] = 0.f;
    for (int f = 0; f < 64; ++f) {
        float pv = pl[t * 65 + f];
#pragma unroll
        for (int r = 0; r < 8; ++r)
            accm[r] += pv * W[f * 64 + g0 + 8 * r];
    }
    float* ob = out + (size_t)d * NTC;
#pragma unroll
    for (int r = 0; r < 8; ++r) {
        int gg = g0 + 8 * r;
        ob[gg * 32 + t] += accm[r];               // block owns node d: safe RMW
    }
}

// ---------------- launch ----------------
// workspace floats:
//   [0, 4194304)        h_in  [b][t][c]
//   [4194304, 8388608)  z     [b][t][c]
//   [8388608, 12582912) p1    [b][t][c]
//   [12582912, +256)    stats
//   [12583168, +16384)  wT4 (padded transposed conv weights)
//   then ints: mode(4) hist(2048) rowp(2052) cur(2048) csrs(32768) csrw(32768)
extern "C" void kernel_launch(void* const* d_in, const int* in_sizes, int n_in,
                              void* d_out, int out_size, void* d_ws, size_t ws_size,
                              hipStream_t stream)
{
    const float* x  = (const float*)d_in[0];
    const int*   ei = (const int*)  d_in[1];
    const float* ew = (const float*)d_in[2];
    const float* cw = (const float*)d_in[3];
    const float* cb = (const float*)d_in[4];
    const float* lg = (const float*)d_in[5];
    const float* lb = (const float*)d_in[6];
    const float* bg = (const float*)d_in[7];
    const float* bb = (const float*)d_in[8];
    const float* tw = (const float*)d_in[9];
    const float* tb = (const float*)d_in[10];
    float* out = (float*)d_out;
    float* ws  = (float*)d_ws;

    float* h_in  = ws;
    float* z     = ws + 4194304;
    float* p1    = ws + 8388608;
    float* stats = ws + 12582912;
    float* wT4   = ws + 12583168;
    int*   ib    = (int*)(ws + 12599552);
    int*   mode  = ib;
    int*   hist  = ib + 4;
    int*   rowp  = ib + 2052;
    int*   cur   = ib + 4104;
    int*   csrs  = ib + 6152;
    float* csrw  = (float*)(ib + 38920);

    hipMemsetAsync(stats, 0, 256 * sizeof(float), stream);
    hipMemsetAsync(ib, 0, 2052 * sizeof(int), stream);   // mode + hist

    k_detect <<<128, 256, 0, stream>>>(ei, mode);
    k_hist   <<<128, 256, 0, stream>>>(ei, mode, hist);
    k_scan   <<<1,   256, 0, stream>>>(hist, rowp, cur, cw, wT4);
    k_scat   <<<128, 256, 0, stream>>>(ei, ew, mode, cur, csrs, csrw);
    k_convln <<<NB,  256, 0, stream>>>(x, wT4, cb, lg, lb, h_in, stats);
    k_bnstats<<<1,    64, 0, stream>>>(stats, bg, bb);
    k_zw0    <<<NB,  256, 0, stream>>>(h_in, stats, tw, tb, z, out);
    k_hop    <<<NB,  256, 0, stream>>>(z,  rowp, csrs, csrw, tw + 4096, p1, out);
    k_hop    <<<NB,  256, 0, stream>>>(p1, rowp, csrs, csrw, tw + 8192, nullptr, out);
}

// Round 3
// 281.235 us; speedup vs baseline: 1.0422x; 1.0422x over previous
//
#include <hip/hip_runtime.h>
#include <cstddef>

// B=2048, C_IN=C_OUT=64, T=32, E=32768, K_HOPS=2, KSIZE=3
#define NB   2048
#define NE   32768
#define NTC  2048      // T*C floats per node
#define SLOPE_F 0.01f
#define EPS_F   1e-5f

__device__ __forceinline__ float rdlane(float v, int lane) {
    return __builtin_bit_cast(float,
        __builtin_amdgcn_readlane(__builtin_bit_cast(int, v), lane));
}

// ---------------- edge-index width handling ----------------
// Reference dtype is int64; harness may hand us int32 or int64. Detect: int64
// (LE) buffers have all-high-words == 0 (node ids < 2048).
__global__ __launch_bounds__(256)
void k_detect(const int* __restrict__ ei, int* __restrict__ mode)
{
    int k = blockIdx.x * 256 + threadIdx.x;
    if (ei[2 * k + 1] != 0) atomicOr(mode, 1);  // 1 => int32 layout
}

__device__ __forceinline__ int edge_src(const int* ei, int m, int e) {
    return m ? ei[e] : ei[2 * e];
}
__device__ __forceinline__ int edge_dst(const int* ei, int m, int e) {
    return m ? ei[NE + e] : ei[2 * (NE + e)];
}

__global__ __launch_bounds__(256)
void k_hist(const int* __restrict__ ei, const int* __restrict__ mode, int* __restrict__ hist)
{
    int e = blockIdx.x * 256 + threadIdx.x;
    int m = *mode;
    atomicAdd(&hist[edge_dst(ei, m, e)], 1);
}

// single block: CSR row-pointer scan + conv-weight transpose to wT4[i][o][4]
__global__ __launch_bounds__(256)
void k_scan(const int* __restrict__ hist, int* __restrict__ rowp, int* __restrict__ cur,
            const float* __restrict__ cw, float* __restrict__ wT4)
{
    __shared__ int part[256];
    int j = threadIdx.x;
    int loc[8]; int s = 0;
#pragma unroll
    for (int r = 0; r < 8; ++r) { loc[r] = hist[j * 8 + r]; s += loc[r]; }
    part[j] = s;
    __syncthreads();
    for (int off = 1; off < 256; off <<= 1) {
        int v = (j >= off) ? part[j - off] : 0;
        __syncthreads();
        part[j] += v;
        __syncthreads();
    }
    int excl = part[j] - s;
#pragma unroll
    for (int r = 0; r < 8; ++r) {
        rowp[j * 8 + r] = excl;
        cur [j * 8 + r] = excl;
        excl += loc[r];
    }
    if (j == 255) rowp[2048] = excl;  // == NE

    // wT4[((i*64)+o)*4 + k] = cw[o*192 + i*3 + k], k<3; pad k=3
    for (int r = 0; r < 64; ++r) {
        int idx = j + r * 256;            // 16384 total
        int i = idx >> 8, o = (idx >> 2) & 63, k = idx & 3;
        wT4[idx] = (k < 3) ? cw[o * 192 + i * 3 + k] : 0.f;
    }
}

__global__ __launch_bounds__(256)
void k_scat(const int* __restrict__ ei, const float* __restrict__ ew,
            const int* __restrict__ mode, int* __restrict__ cur,
            int* __restrict__ csrs, float* __restrict__ csrw)
{
    int e = blockIdx.x * 256 + threadIdx.x;
    int m = *mode;
    int d = edge_dst(ei, m, e);
    int pos = atomicAdd(&cur[d], 1);
    csrs[pos] = edge_src(ei, m, e);
    csrw[pos] = ew[e];
}

// ---------------- conv1d + leaky + LayerNorm + BN partials ----------------
// One block per b. Main loop is LDS-free: lane l holds x-row i=l's 10-float
// t-window in registers; rows are broadcast with v_readlane (VALU pipe).
// Weights prefetched 4 rows ahead from global (L1/L2-hit, coalesced 1KB/wave).
__global__ __launch_bounds__(256, 6)
void k_convln(const float* __restrict__ x, const float* __restrict__ wT4,
              const float* __restrict__ cb, const float* __restrict__ lg,
              const float* __restrict__ lb, float* __restrict__ h_in,
              float* __restrict__ stats)
{
    __shared__ __align__(16) float xp[64 * 36];   // xp[i][t+2]=x[i][t], zero pad
    __shared__ float red1[64], red2[64];
    __shared__ float wsum[8];
    __shared__ float bcast[2];

    const int b = blockIdx.x, j = threadIdx.x;
    const float* xb = x + (size_t)b * NTC;

#pragma unroll
    for (int r = 0; r < 8; ++r) {
        int idx = j + r * 256;                    // i = idx>>5, t = idx&31
        xp[(idx >> 5) * 36 + (idx & 31) + 2] = xb[idx];
    }
    {
        int i = j >> 2, s = j & 3;
        xp[i * 36 + ((s < 2) ? s : 32 + s)] = 0.f;  // zero pad slots 0,1,34,35
    }
    if (j < 64) { red1[j] = 0.f; red2[j] = 0.f; }
    __syncthreads();

    const int o = j & 63, l = j & 63, g = j >> 6;
    const int t0 = g * 8;                         // channel o, t in [t0,t0+8)

    // lane l: register copy of xp[l][t0 .. t0+9]  (one-time LDS read)
    float xq[10];
    {
        const float* myrow = &xp[l * 36 + t0];    // 36%4==0 -> 16B aligned
        float4 qa = *(const float4*)(myrow);
        float4 qb = *(const float4*)(myrow + 4);
        float2 qc = *(const float2*)(myrow + 8);
        xq[0]=qa.x; xq[1]=qa.y; xq[2]=qa.z; xq[3]=qa.w;
        xq[4]=qb.x; xq[5]=qb.y; xq[6]=qb.z; xq[7]=qb.w;
        xq[8]=qc.x; xq[9]=qc.y;
    }

    float acc[8];
    {
        float cbv = cb[o];
#pragma unroll
        for (int r = 0; r < 8; ++r) acc[r] = cbv;
    }
    const float4* wrow = (const float4*)wT4 + o;  // stride 64 float4s per i
    for (int ib = 0; ib < 16; ++ib) {
        float4 w0 = wrow[(ib * 4 + 0) * 64];
        float4 w1 = wrow[(ib * 4 + 1) * 64];
        float4 w2 = wrow[(ib * 4 + 2) * 64];
        float4 w3 = wrow[(ib * 4 + 3) * 64];
#pragma unroll
        for (int k = 0; k < 4; ++k) {
            const int i = ib * 4 + k;
            float4 wv = (k == 0) ? w0 : (k == 1) ? w1 : (k == 2) ? w2 : w3;
            float xs[10];
#pragma unroll
            for (int s = 0; s < 10; ++s) xs[s] = rdlane(xq[s], i);
#pragma unroll
            for (int r = 0; r < 8; ++r)
                acc[r] += xs[r]*wv.x + xs[r+1]*wv.y + xs[r+2]*wv.z;
        }
    }
    // leaky relu + local LN stats
    float s1 = 0.f, s2 = 0.f;
#pragma unroll
    for (int r = 0; r < 8; ++r) {
        float v = acc[r];
        v = (v >= 0.f) ? v : SLOPE_F * v;
        acc[r] = v;
        s1 += v; s2 += v * v;
    }
#pragma unroll
    for (int off = 32; off > 0; off >>= 1) {
        s1 += __shfl_down(s1, off, 64);
        s2 += __shfl_down(s2, off, 64);
    }
    if ((j & 63) == 0) { wsum[j >> 6] = s1; wsum[4 + (j >> 6)] = s2; }
    __syncthreads();
    if (j == 0) {
        float S1 = wsum[0] + wsum[1] + wsum[2] + wsum[3];
        float S2 = wsum[4] + wsum[5] + wsum[6] + wsum[7];
        float mu  = S1 * (1.f / 2048.f);
        float var = S2 * (1.f / 2048.f) - mu * mu;
        bcast[0] = mu;
        bcast[1] = rsqrtf(var + EPS_F);
    }
    __syncthreads();
    const float mu = bcast[0], rs = bcast[1];
    float hs1 = 0.f, hs2 = 0.f;
    float* hb = h_in + (size_t)b * NTC;
#pragma unroll
    for (int r = 0; r < 8; ++r) {
        int t = t0 + r;
        float h = (acc[r] - mu) * rs * lg[o * 32 + t] + lb[o * 32 + t];
        hb[t * 64 + o] = h;                        // coalesced: lanes span o
        hs1 += h; hs2 += h * h;
    }
    atomicAdd(&red1[o], hs1);
    atomicAdd(&red2[o], hs2);
    __syncthreads();
    if (j < 64)       atomicAdd(&stats[j], red1[j]);
    else if (j < 128) atomicAdd(&stats[j], red2[j - 64]);
}

// ---------------- BN stats -> scale/shift ----------------
__global__ void k_bnstats(float* __restrict__ stats, const float* __restrict__ bg,
                          const float* __restrict__ bb)
{
    int c = threadIdx.x;            // 64 threads
    const float inv_n = 1.f / 65536.f;
    float mu  = stats[c] * inv_n;
    float var = stats[64 + c] * inv_n - mu * mu;
    float rs  = rsqrtf(var + EPS_F);
    float sc  = bg[c] * rs;
    stats[128 + c] = sc;
    stats[192 + c] = bb[c] - mu * sc;
}

// ---------------- z = leaky(BN(h)); out = h + z@W0 + tag_b ----------------
// Thread owns 8 CONSECUTIVE outputs g = gq..gq+7 so W-row reads are 2x
// ds_read_b128 (half-wave-uniform, conflict-free) instead of 8x b32.
__global__ __launch_bounds__(256, 4)
void k_zw0(const float* __restrict__ h_in, const float* __restrict__ stats,
           const float* __restrict__ tw, const float* __restrict__ tb,
           float* __restrict__ z, float* __restrict__ out)
{
    __shared__ float zl[32 * 65];
    __shared__ float hl[32 * 65];
    __shared__ __align__(16) float W[64 * 64];
    const int b = blockIdx.x, j = threadIdx.x;
#pragma unroll
    for (int r = 0; r < 16; ++r) { int idx = j + r * 256; W[idx] = tw[idx]; }
    const int c = j & 63;
    const float sc = stats[128 + c], sh = stats[192 + c];
    const float* hb = h_in + (size_t)b * NTC;
    float* zb = z + (size_t)b * NTC;
#pragma unroll
    for (int r = 0; r < 8; ++r) {
        int idx = j + r * 256;                    // idx = t*64 + c
        int t = idx >> 6;
        float h = hb[idx];
        float zv = h * sc + sh;
        zv = (zv >= 0.f) ? zv : SLOPE_F * zv;
        zb[idx] = zv;
        zl[t * 65 + c] = zv;
        hl[t * 65 + c] = h;
    }
    __syncthreads();
    const int t = j & 31, gq = (j >> 5) * 8;      // outputs (t, gq..gq+7)
    float accm[8];
#pragma unroll
    for (int r = 0; r < 8; ++r)
        accm[r] = tb[gq + r] + hl[t * 65 + gq + r];   // residual + bias
    for (int f = 0; f < 64; ++f) {
        float zv = zl[t * 65 + f];
        const float4* Wr = (const float4*)&W[f * 64 + gq];
        float4 wa = Wr[0], wb = Wr[1];
        accm[0] += zv*wa.x; accm[1] += zv*wa.y; accm[2] += zv*wa.z; accm[3] += zv*wa.w;
        accm[4] += zv*wb.x; accm[5] += zv*wb.y; accm[6] += zv*wb.z; accm[7] += zv*wb.w;
    }
    float* ob = out + (size_t)b * NTC;            // out layout [b][c][t]
#pragma unroll
    for (int r = 0; r < 8; ++r)
        ob[(gq + r) * 32 + t] = accm[r];          // coalesced: lanes span t
}

// ---------------- one propagation hop + fused matmul into out ----------------
__global__ __launch_bounds__(256, 6)
void k_hop(const float* __restrict__ p_in, const int* __restrict__ rowp,
           const int* __restrict__ csrs, const float* __restrict__ csrw,
           const float* __restrict__ tw, float* __restrict__ p_out,
           float* __restrict__ out)
{
    __shared__ float pl[32 * 65];
    __shared__ __align__(16) float W[64 * 64];
    const int d = blockIdx.x, j = threadIdx.x;
#pragma unroll
    for (int r = 0; r < 16; ++r) { int idx = j + r * 256; W[idx] = tw[idx]; }
    const int beg = rowp[d], end = rowp[d + 1];
    float4 a0 = make_float4(0.f,0.f,0.f,0.f), a1 = make_float4(0.f,0.f,0.f,0.f);
    float4 b0 = make_float4(0.f,0.f,0.f,0.f), b1 = make_float4(0.f,0.f,0.f,0.f);
    int e = beg;
    for (; e + 2 <= end; e += 2) {                // 2-edge unroll: 4 loads in flight
        int s0_ = csrs[e],   s1_ = csrs[e+1];
        float w0 = csrw[e],  w1 = csrw[e+1];
        const float4* pb0 = (const float4*)(p_in + (size_t)s0_ * NTC);
        const float4* pb1 = (const float4*)(p_in + (size_t)s1_ * NTC);
        float4 v00 = pb0[j], v01 = pb0[j + 256];
        float4 v10 = pb1[j], v11 = pb1[j + 256];
        a0.x += w0*v00.x; a0.y += w0*v00.y; a0.z += w0*v00.z; a0.w += w0*v00.w;
        a1.x += w0*v01.x; a1.y += w0*v01.y; a1.z += w0*v01.z; a1.w += w0*v01.w;
        b0.x += w1*v10.x; b0.y += w1*v10.y; b0.z += w1*v10.z; b0.w += w1*v10.w;
        b1.x += w1*v11.x; b1.y += w1*v11.y; b1.z += w1*v11.z; b1.w += w1*v11.w;
    }
    if (e < end) {
        int s0_ = csrs[e];
        float w0 = csrw[e];
        const float4* pb0 = (const float4*)(p_in + (size_t)s0_ * NTC);
        float4 v00 = pb0[j], v01 = pb0[j + 256];
        a0.x += w0*v00.x; a0.y += w0*v00.y; a0.z += w0*v00.z; a0.w += w0*v00.w;
        a1.x += w0*v01.x; a1.y += w0*v01.y; a1.z += w0*v01.z; a1.w += w0*v01.w;
    }
    a0.x += b0.x; a0.y += b0.y; a0.z += b0.z; a0.w += b0.w;
    a1.x += b1.x; a1.y += b1.y; a1.z += b1.z; a1.w += b1.w;

    if (p_out) {
        float4* po = (float4*)(p_out + (size_t)d * NTC);
        po[j] = a0;
        po[j + 256] = a1;
    }
    {
        int idx = j * 4;
        int t = idx >> 6, c = idx & 63;
        float* q = &pl[t * 65 + c];
        q[0] = a0.x; q[1] = a0.y; q[2] = a0.z; q[3] = a0.w;
        idx = j * 4 + 1024; t = idx >> 6; c = idx & 63;
        q = &pl[t * 65 + c];
        q[0] = a1.x; q[1] = a1.y; q[2] = a1.z; q[3] = a1.w;
    }
    __syncthreads();
    const int t = j & 31, gq = (j >> 5) * 8;
    float accm[8];
#pragma unroll
    for (int r = 0; r < 8; ++r) accm[r] = 0.f;
    for (int f = 0; f < 64; ++f) {
        float pv = pl[t * 65 + f];
        const float4* Wr = (const float4*)&W[f * 64 + gq];
        float4 wa = Wr[0], wb = Wr[1];
        accm[0] += pv*wa.x; accm[1] += pv*wa.y; accm[2] += pv*wa.z; accm[3] += pv*wa.w;
        accm[4] += pv*wb.x; accm[5] += pv*wb.y; accm[6] += pv*wb.z; accm[7] += pv*wb.w;
    }
    float* ob = out + (size_t)d * NTC;
#pragma unroll
    for (int r = 0; r < 8; ++r)
        ob[(gq + r) * 32 + t] += accm[r];         // block owns node d: safe RMW
}

// ---------------- launch ----------------
// workspace floats:
//   [0, 4194304)        h_in  [b][t][c]
//   [4194304, 8388608)  z     [b][t][c]
//   [8388608, 12582912) p1    [b][t][c]
//   [12582912, +256)    stats
//   [12583168, +16384)  wT4 (padded transposed conv weights)
//   then ints: mode(4) hist(2048) rowp(2052) cur(2048) csrs(32768) csrw(32768)
extern "C" void kernel_launch(void* const* d_in, const int* in_sizes, int n_in,
                              void* d_out, int out_size, void* d_ws, size_t ws_size,
                              hipStream_t stream)
{
    const float* x  = (const float*)d_in[0];
    const int*   ei = (const int*)  d_in[1];
    const float* ew = (const float*)d_in[2];
    const float* cw = (const float*)d_in[3];
    const float* cb = (const float*)d_in[4];
    const float* lg = (const float*)d_in[5];
    const float* lb = (const float*)d_in[6];
    const float* bg = (const float*)d_in[7];
    const float* bb = (const float*)d_in[8];
    const float* tw = (const float*)d_in[9];
    const float* tb = (const float*)d_in[10];
    float* out = (float*)d_out;
    float* ws  = (float*)d_ws;

    float* h_in  = ws;
    float* z     = ws + 4194304;
    float* p1    = ws + 8388608;
    float* stats = ws + 12582912;
    float* wT4   = ws + 12583168;
    int*   ib    = (int*)(ws + 12599552);
    int*   mode  = ib;
    int*   hist  = ib + 4;
    int*   rowp  = ib + 2052;
    int*   cur   = ib + 4104;
    int*   csrs  = ib + 6152;
    float* csrw  = (float*)(ib + 38920);

    hipMemsetAsync(stats, 0, 256 * sizeof(float), stream);
    hipMemsetAsync(ib, 0, 2052 * sizeof(int), stream);   // mode + hist

    k_detect <<<128, 256, 0, stream>>>(ei, mode);
    k_hist   <<<128, 256, 0, stream>>>(ei, mode, hist);
    k_scan   <<<1,   256, 0, stream>>>(hist, rowp, cur, cw, wT4);
    k_scat   <<<128, 256, 0, stream>>>(ei, ew, mode, cur, csrs, csrw);
    k_convln <<<NB,  256, 0, stream>>>(x, wT4, cb, lg, lb, h_in, stats);
    k_bnstats<<<1,    64, 0, stream>>>(stats, bg, bb);
    k_zw0    <<<NB,  256, 0, stream>>>(h_in, stats, tw, tb, z, out);
    k_hop    <<<NB,  256, 0, stream>>>(z,  rowp, csrs, csrw, tw + 4096, p1, out);
    k_hop    <<<NB,  256, 0, stream>>>(p1, rowp, csrs, csrw, tw + 8192, nullptr, out);
}

// Round 4
// 259.596 us; speedup vs baseline: 1.1291x; 1.0834x over previous
//
#include <hip/hip_runtime.h>
#include <cstddef>

// B=2048, C_IN=C_OUT=64, T=32, E=32768, K_HOPS=2, KSIZE=3
#define NB   2048
#define NE   32768
#define NTC  2048      // T*C floats per node
#define SLOPE_F 0.01f
#define EPS_F   1e-5f

__device__ __forceinline__ float rdlane(float v, int lane) {
    return __builtin_bit_cast(float,
        __builtin_amdgcn_readlane(__builtin_bit_cast(int, v), lane));
}

// ---------------- edge-index width handling ----------------
__global__ __launch_bounds__(256)
void k_detect(const int* __restrict__ ei, int* __restrict__ mode)
{
    int k = blockIdx.x * 256 + threadIdx.x;
    if (ei[2 * k + 1] != 0) atomicOr(mode, 1);  // 1 => int32 layout
}

__device__ __forceinline__ int edge_src(const int* ei, int m, int e) {
    return m ? ei[e] : ei[2 * e];
}
__device__ __forceinline__ int edge_dst(const int* ei, int m, int e) {
    return m ? ei[NE + e] : ei[2 * (NE + e)];
}

__global__ __launch_bounds__(256)
void k_hist(const int* __restrict__ ei, const int* __restrict__ mode, int* __restrict__ hist)
{
    int e = blockIdx.x * 256 + threadIdx.x;
    int m = *mode;
    atomicAdd(&hist[edge_dst(ei, m, e)], 1);
}

// single block: CSR row-pointer scan + conv-weight transpose to wT4[i][o][4]
__global__ __launch_bounds__(256)
void k_scan(const int* __restrict__ hist, int* __restrict__ rowp, int* __restrict__ cur,
            const float* __restrict__ cw, float* __restrict__ wT4)
{
    __shared__ int part[256];
    int j = threadIdx.x;
    int loc[8]; int s = 0;
#pragma unroll
    for (int r = 0; r < 8; ++r) { loc[r] = hist[j * 8 + r]; s += loc[r]; }
    part[j] = s;
    __syncthreads();
    for (int off = 1; off < 256; off <<= 1) {
        int v = (j >= off) ? part[j - off] : 0;
        __syncthreads();
        part[j] += v;
        __syncthreads();
    }
    int excl = part[j] - s;
#pragma unroll
    for (int r = 0; r < 8; ++r) {
        rowp[j * 8 + r] = excl;
        cur [j * 8 + r] = excl;
        excl += loc[r];
    }
    if (j == 255) rowp[2048] = excl;  // == NE

    // wT4[((i*64)+o)*4 + k] = cw[o*192 + i*3 + k], k<3; pad k=3
    for (int r = 0; r < 64; ++r) {
        int idx = j + r * 256;            // 16384 total
        int i = idx >> 8, o = (idx >> 2) & 63, k = idx & 3;
        wT4[idx] = (k < 3) ? cw[o * 192 + i * 3 + k] : 0.f;
    }
}

__global__ __launch_bounds__(256)
void k_scat(const int* __restrict__ ei, const float* __restrict__ ew,
            const int* __restrict__ mode, int* __restrict__ cur,
            int* __restrict__ csrs, float* __restrict__ csrw)
{
    int e = blockIdx.x * 256 + threadIdx.x;
    int m = *mode;
    int d = edge_dst(ei, m, e);
    int pos = atomicAdd(&cur[d], 1);
    csrs[pos] = edge_src(ei, m, e);
    csrw[pos] = ew[e];
}

// ---------------- conv1d + leaky + LayerNorm + BN partials ----------------
// One block per b. BN partials go to partials[b][0..127] as ONE coalesced
// plain store per block — NO contended global atomics (R3 post-mortem: the
// 262144 same-address fp32 atomics were a ~70us serialization floor).
__global__ __launch_bounds__(256, 6)
void k_convln(const float* __restrict__ x, const float* __restrict__ wT4,
              const float* __restrict__ cb, const float* __restrict__ lg,
              const float* __restrict__ lb, float* __restrict__ h_in,
              float* __restrict__ partials)
{
    __shared__ __align__(16) float xp[64 * 36];   // xp[i][t+2]=x[i][t], zero pad
    __shared__ float red1[64], red2[64];
    __shared__ float wsum[8];
    __shared__ float bcast[2];

    const int b = blockIdx.x, j = threadIdx.x;
    const float* xb = x + (size_t)b * NTC;

#pragma unroll
    for (int r = 0; r < 8; ++r) {
        int idx = j + r * 256;                    // i = idx>>5, t = idx&31
        xp[(idx >> 5) * 36 + (idx & 31) + 2] = xb[idx];
    }
    {
        int i = j >> 2, s = j & 3;
        xp[i * 36 + ((s < 2) ? s : 32 + s)] = 0.f;  // zero pad slots 0,1,34,35
    }
    if (j < 64) { red1[j] = 0.f; red2[j] = 0.f; }
    __syncthreads();

    const int o = j & 63, l = j & 63, g = j >> 6;
    const int t0 = g * 8;                         // channel o, t in [t0,t0+8)

    // lane l: register copy of xp[l][t0 .. t0+9]  (one-time LDS read)
    float xq[10];
    {
        const float* myrow = &xp[l * 36 + t0];
        float4 qa = *(const float4*)(myrow);
        float4 qb = *(const float4*)(myrow + 4);
        float2 qc = *(const float2*)(myrow + 8);
        xq[0]=qa.x; xq[1]=qa.y; xq[2]=qa.z; xq[3]=qa.w;
        xq[4]=qb.x; xq[5]=qb.y; xq[6]=qb.z; xq[7]=qb.w;
        xq[8]=qc.x; xq[9]=qc.y;
    }

    float acc[8];
    {
        float cbv = cb[o];
#pragma unroll
        for (int r = 0; r < 8; ++r) acc[r] = cbv;
    }
    const float4* wrow = (const float4*)wT4 + o;  // stride 64 float4s per i
    for (int ib = 0; ib < 16; ++ib) {
        float4 w0 = wrow[(ib * 4 + 0) * 64];
        float4 w1 = wrow[(ib * 4 + 1) * 64];
        float4 w2 = wrow[(ib * 4 + 2) * 64];
        float4 w3 = wrow[(ib * 4 + 3) * 64];
#pragma unroll
        for (int k = 0; k < 4; ++k) {
            const int i = ib * 4 + k;
            float4 wv = (k == 0) ? w0 : (k == 1) ? w1 : (k == 2) ? w2 : w3;
            float xs[10];
#pragma unroll
            for (int s = 0; s < 10; ++s) xs[s] = rdlane(xq[s], i);
#pragma unroll
            for (int r = 0; r < 8; ++r)
                acc[r] += xs[r]*wv.x + xs[r+1]*wv.y + xs[r+2]*wv.z;
        }
    }
    // leaky relu + local LN stats
    float s1 = 0.f, s2 = 0.f;
#pragma unroll
    for (int r = 0; r < 8; ++r) {
        float v = acc[r];
        v = (v >= 0.f) ? v : SLOPE_F * v;
        acc[r] = v;
        s1 += v; s2 += v * v;
    }
#pragma unroll
    for (int off = 32; off > 0; off >>= 1) {
        s1 += __shfl_down(s1, off, 64);
        s2 += __shfl_down(s2, off, 64);
    }
    if ((j & 63) == 0) { wsum[j >> 6] = s1; wsum[4 + (j >> 6)] = s2; }
    __syncthreads();
    if (j == 0) {
        float S1 = wsum[0] + wsum[1] + wsum[2] + wsum[3];
        float S2 = wsum[4] + wsum[5] + wsum[6] + wsum[7];
        float mu  = S1 * (1.f / 2048.f);
        float var = S2 * (1.f / 2048.f) - mu * mu;
        bcast[0] = mu;
        bcast[1] = rsqrtf(var + EPS_F);
    }
    __syncthreads();
    const float mu = bcast[0], rs = bcast[1];
    float hs1 = 0.f, hs2 = 0.f;
    float* hb = h_in + (size_t)b * NTC;
#pragma unroll
    for (int r = 0; r < 8; ++r) {
        int t = t0 + r;
        float h = (acc[r] - mu) * rs * lg[o * 32 + t] + lb[o * 32 + t];
        hb[t * 64 + o] = h;                        // coalesced: lanes span o
        hs1 += h; hs2 += h * h;
    }
    atomicAdd(&red1[o], hs1);                      // LDS atomics only
    atomicAdd(&red2[o], hs2);
    __syncthreads();
    float* pb_ = partials + (size_t)b * 128;       // coalesced 512B plain store
    if (j < 64)       pb_[j]      = red1[j];
    else if (j < 128) pb_[j]      = red2[j - 64];
}

// ---------------- reduce partials -> BN scale/shift ----------------
// 64 blocks: block c sums partials[b][c] and partials[b][64+c] over b.
__global__ __launch_bounds__(256)
void k_bnred(const float* __restrict__ partials, const float* __restrict__ bg,
             const float* __restrict__ bb, float* __restrict__ stats)
{
    const int c = blockIdx.x, j = threadIdx.x;
    float s1 = 0.f, s2 = 0.f;
    for (int b = j; b < NB; b += 256) {
        const float* p = partials + (size_t)b * 128;
        s1 += p[c];
        s2 += p[64 + c];
    }
    __shared__ float r1[4], r2[4];
#pragma unroll
    for (int off = 32; off > 0; off >>= 1) {
        s1 += __shfl_down(s1, off, 64);
        s2 += __shfl_down(s2, off, 64);
    }
    if ((j & 63) == 0) { r1[j >> 6] = s1; r2[j >> 6] = s2; }
    __syncthreads();
    if (j == 0) {
        float S1 = r1[0] + r1[1] + r1[2] + r1[3];
        float S2 = r2[0] + r2[1] + r2[2] + r2[3];
        const float inv_n = 1.f / 65536.f;
        float mu  = S1 * inv_n;
        float var = S2 * inv_n - mu * mu;
        float rs  = rsqrtf(var + EPS_F);
        float sc  = bg[c] * rs;
        stats[128 + c] = sc;
        stats[192 + c] = bb[c] - mu * sc;
    }
}

// ---------------- z = leaky(BN(h)); out = h + z@W0 + tag_b ----------------
__global__ __launch_bounds__(256, 4)
void k_zw0(const float* __restrict__ h_in, const float* __restrict__ stats,
           const float* __restrict__ tw, const float* __restrict__ tb,
           float* __restrict__ z, float* __restrict__ out)
{
    __shared__ float zl[32 * 65];
    __shared__ float hl[32 * 65];
    __shared__ __align__(16) float W[64 * 64];
    const int b = blockIdx.x, j = threadIdx.x;
#pragma unroll
    for (int r = 0; r < 16; ++r) { int idx = j + r * 256; W[idx] = tw[idx]; }
    const int c = j & 63;
    const float sc = stats[128 + c], sh = stats[192 + c];
    const float* hb = h_in + (size_t)b * NTC;
    float* zb = z + (size_t)b * NTC;
#pragma unroll
    for (int r = 0; r < 8; ++r) {
        int idx = j + r * 256;                    // idx = t*64 + c
        int t = idx >> 6;
        float h = hb[idx];
        float zv = h * sc + sh;
        zv = (zv >= 0.f) ? zv : SLOPE_F * zv;
        zb[idx] = zv;
        zl[t * 65 + c] = zv;
        hl[t * 65 + c] = h;
    }
    __syncthreads();
    const int t = j & 31, gq = (j >> 5) * 8;      // outputs (t, gq..gq+7)
    float accm[8];
#pragma unroll
    for (int r = 0; r < 8; ++r)
        accm[r] = tb[gq + r] + hl[t * 65 + gq + r];   // residual + bias
    for (int f = 0; f < 64; ++f) {
        float zv = zl[t * 65 + f];
        const float4* Wr = (const float4*)&W[f * 64 + gq];
        float4 wa = Wr[0], wb = Wr[1];
        accm[0] += zv*wa.x; accm[1] += zv*wa.y; accm[2] += zv*wa.z; accm[3] += zv*wa.w;
        accm[4] += zv*wb.x; accm[5] += zv*wb.y; accm[6] += zv*wb.z; accm[7] += zv*wb.w;
    }
    float* ob = out + (size_t)b * NTC;            // out layout [b][c][t]
#pragma unroll
    for (int r = 0; r < 8; ++r)
        ob[(gq + r) * 32 + t] = accm[r];          // coalesced: lanes span t
}

// ---------------- one propagation hop + fused matmul into out ----------------
__global__ __launch_bounds__(256, 6)
void k_hop(const float* __restrict__ p_in, const int* __restrict__ rowp,
           const int* __restrict__ csrs, const float* __restrict__ csrw,
           const float* __restrict__ tw, float* __restrict__ p_out,
           float* __restrict__ out)
{
    __shared__ float pl[32 * 65];
    __shared__ __align__(16) float W[64 * 64];
    const int d = blockIdx.x, j = threadIdx.x;
#pragma unroll
    for (int r = 0; r < 16; ++r) { int idx = j + r * 256; W[idx] = tw[idx]; }
    const int beg = rowp[d], end = rowp[d + 1];
    float4 a0 = make_float4(0.f,0.f,0.f,0.f), a1 = make_float4(0.f,0.f,0.f,0.f);
    float4 b0 = make_float4(0.f,0.f,0.f,0.f), b1 = make_float4(0.f,0.f,0.f,0.f);
    int e = beg;
    for (; e + 2 <= end; e += 2) {                // 2-edge unroll
        int s0_ = csrs[e],   s1_ = csrs[e+1];
        float w0 = csrw[e],  w1 = csrw[e+1];
        const float4* pb0 = (const float4*)(p_in + (size_t)s0_ * NTC);
        const float4* pb1 = (const float4*)(p_in + (size_t)s1_ * NTC);
        float4 v00 = pb0[j], v01 = pb0[j + 256];
        float4 v10 = pb1[j], v11 = pb1[j + 256];
        a0.x += w0*v00.x; a0.y += w0*v00.y; a0.z += w0*v00.z; a0.w += w0*v00.w;
        a1.x += w0*v01.x; a1.y += w0*v01.y; a1.z += w0*v01.z; a1.w += w0*v01.w;
        b0.x += w1*v10.x; b0.y += w1*v10.y; b0.z += w1*v10.z; b0.w += w1*v10.w;
        b1.x += w1*v11.x; b1.y += w1*v11.y; b1.z += w1*v11.z; b1.w += w1*v11.w;
    }
    if (e < end) {
        int s0_ = csrs[e];
        float w0 = csrw[e];
        const float4* pb0 = (const float4*)(p_in + (size_t)s0_ * NTC);
        float4 v00 = pb0[j], v01 = pb0[j + 256];
        a0.x += w0*v00.x; a0.y += w0*v00.y; a0.z += w0*v00.z; a0.w += w0*v00.w;
        a1.x += w0*v01.x; a1.y += w0*v01.y; a1.z += w0*v01.z; a1.w += w0*v01.w;
    }
    a0.x += b0.x; a0.y += b0.y; a0.z += b0.z; a0.w += b0.w;
    a1.x += b1.x; a1.y += b1.y; a1.z += b1.z; a1.w += b1.w;

    if (p_out) {
        float4* po = (float4*)(p_out + (size_t)d * NTC);
        po[j] = a0;
        po[j + 256] = a1;
    }
    {
        int idx = j * 4;
        int t = idx >> 6, c = idx & 63;
        float* q = &pl[t * 65 + c];
        q[0] = a0.x; q[1] = a0.y; q[2] = a0.z; q[3] = a0.w;
        idx = j * 4 + 1024; t = idx >> 6; c = idx & 63;
        q = &pl[t * 65 + c];
        q[0] = a1.x; q[1] = a1.y; q[2] = a1.z; q[3] = a1.w;
    }
    __syncthreads();
    const int t = j & 31, gq = (j >> 5) * 8;
    float accm[8];
#pragma unroll
    for (int r = 0; r < 8; ++r) accm[r] = 0.f;
    for (int f = 0; f < 64; ++f) {
        float pv = pl[t * 65 + f];
        const float4* Wr = (const float4*)&W[f * 64 + gq];
        float4 wa = Wr[0], wb = Wr[1];
        accm[0] += pv*wa.x; accm[1] += pv*wa.y; accm[2] += pv*wa.z; accm[3] += pv*wa.w;
        accm[4] += pv*wb.x; accm[5] += pv*wb.y; accm[6] += pv*wb.z; accm[7] += pv*wb.w;
    }
    float* ob = out + (size_t)d * NTC;
#pragma unroll
    for (int r = 0; r < 8; ++r)
        ob[(gq + r) * 32 + t] += accm[r];         // block owns node d: safe RMW
}

// ---------------- launch ----------------
// workspace floats (p1 aliases h_in — h_in is dead after k_zw0):
//   [0, 4194304)        h_in [b][t][c]  /  p1 [b][t][c]
//   [4194304, 8388608)  z    [b][t][c]
//   [8388608, +256)     stats (scale[64]@128, shift[64]@192)
//   [8388864, +16384)   wT4
//   [8405248, +262144)  partials [b][128]
//   [8667392, ...)      ints: mode(4) hist(2048) rowp(2052) cur(2048)
//                             csrs(32768) csrw(32768)        (~35 MiB total)
extern "C" void kernel_launch(void* const* d_in, const int* in_sizes, int n_in,
                              void* d_out, int out_size, void* d_ws, size_t ws_size,
                              hipStream_t stream)
{
    const float* x  = (const float*)d_in[0];
    const int*   ei = (const int*)  d_in[1];
    const float* ew = (const float*)d_in[2];
    const float* cw = (const float*)d_in[3];
    const float* cb = (const float*)d_in[4];
    const float* lg = (const float*)d_in[5];
    const float* lb = (const float*)d_in[6];
    const float* bg = (const float*)d_in[7];
    const float* bb = (const float*)d_in[8];
    const float* tw = (const float*)d_in[9];
    const float* tb = (const float*)d_in[10];
    float* out = (float*)d_out;
    float* ws  = (float*)d_ws;

    float* h_in  = ws;
    float* p1    = ws;                 // alias: h_in dead after k_zw0
    float* z     = ws + 4194304;
    float* stats = ws + 8388608;
    float* wT4   = ws + 8388864;
    float* parts = ws + 8405248;
    int*   ib    = (int*)(ws + 8667392);
    int*   mode  = ib;
    int*   hist  = ib + 4;
    int*   rowp  = ib + 2052;
    int*   cur   = ib + 4104;
    int*   csrs  = ib + 6152;
    float* csrw  = (float*)(ib + 38920);

    hipMemsetAsync(ib, 0, 2052 * sizeof(int), stream);   // mode + hist

    k_detect <<<128, 256, 0, stream>>>(ei, mode);
    k_hist   <<<128, 256, 0, stream>>>(ei, mode, hist);
    k_scan   <<<1,   256, 0, stream>>>(hist, rowp, cur, cw, wT4);
    k_scat   <<<128, 256, 0, stream>>>(ei, ew, mode, cur, csrs, csrw);
    k_convln <<<NB,  256, 0, stream>>>(x, wT4, cb, lg, lb, h_in, parts);
    k_bnred  <<<64,  256, 0, stream>>>(parts, bg, bb, stats);
    k_zw0    <<<NB,  256, 0, stream>>>(h_in, stats, tw, tb, z, out);
    k_hop    <<<NB,  256, 0, stream>>>(z,  rowp, csrs, csrw, tw + 4096, p1, out);
    k_hop    <<<NB,  256, 0, stream>>>(p1, rowp, csrs, csrw, tw + 8192, nullptr, out);
}

// Round 5
// 243.919 us; speedup vs baseline: 1.2017x; 1.0643x over previous
//
#include <hip/hip_runtime.h>
#include <cstddef>

// B=2048, C_IN=C_OUT=64, T=32, E=32768, K_HOPS=2, KSIZE=3
#define NB   2048
#define NE   32768
#define NTC  2048      // T*C floats per node
#define SLOPE_F 0.01f
#define EPS_F   1e-5f

// ---------------- edge-index width handling ----------------
__global__ __launch_bounds__(256)
void k_detect(const int* __restrict__ ei, int* __restrict__ mode)
{
    int k = blockIdx.x * 256 + threadIdx.x;
    if (ei[2 * k + 1] != 0) atomicOr(mode, 1);  // 1 => int32 layout
}

__device__ __forceinline__ int edge_src(const int* ei, int m, int e) {
    return m ? ei[e] : ei[2 * e];
}
__device__ __forceinline__ int edge_dst(const int* ei, int m, int e) {
    return m ? ei[NE + e] : ei[2 * (NE + e)];
}

// hist + (first 64 blocks) conv-weight transpose to wT4[i][o][4]
// (moved off the single-block k_scan serial path)
__global__ __launch_bounds__(256)
void k_hist(const int* __restrict__ ei, const int* __restrict__ mode,
            int* __restrict__ hist, const float* __restrict__ cw,
            float* __restrict__ wT4)
{
    int e = blockIdx.x * 256 + threadIdx.x;
    int m = *mode;
    atomicAdd(&hist[edge_dst(ei, m, e)], 1);
    if (blockIdx.x < 64) {
        int idx = e;                      // 0..16383
        int i = idx >> 8, o = (idx >> 2) & 63, k = idx & 3;
        wT4[idx] = (k < 3) ? cw[o * 192 + i * 3 + k] : 0.f;
    }
}

// single block: CSR row-pointer scan
__global__ __launch_bounds__(256)
void k_scan(const int* __restrict__ hist, int* __restrict__ rowp, int* __restrict__ cur)
{
    __shared__ int part[256];
    int j = threadIdx.x;
    int loc[8]; int s = 0;
#pragma unroll
    for (int r = 0; r < 8; ++r) { loc[r] = hist[j * 8 + r]; s += loc[r]; }
    part[j] = s;
    __syncthreads();
    for (int off = 1; off < 256; off <<= 1) {
        int v = (j >= off) ? part[j - off] : 0;
        __syncthreads();
        part[j] += v;
        __syncthreads();
    }
    int excl = part[j] - s;
#pragma unroll
    for (int r = 0; r < 8; ++r) {
        rowp[j * 8 + r] = excl;
        cur [j * 8 + r] = excl;
        excl += loc[r];
    }
    if (j == 255) rowp[2048] = excl;  // == NE
}

__global__ __launch_bounds__(256)
void k_scat(const int* __restrict__ ei, const float* __restrict__ ew,
            const int* __restrict__ mode, int* __restrict__ cur,
            int* __restrict__ csrs, float* __restrict__ csrw)
{
    int e = blockIdx.x * 256 + threadIdx.x;
    int m = *mode;
    int d = edge_dst(ei, m, e);
    int pos = atomicAdd(&cur[d], 1);
    csrs[pos] = edge_src(ei, m, e);
    csrw[pos] = ew[e];
}

// ---------------- conv1d + leaky + LayerNorm + BN partials ----------------
// One block per b. x-window comes from LDS via WAVE-UNIFORM reads (all 64
// lanes of a wave share t0 -> pure broadcast, no conflicts, no VALU cost).
// R4 post-mortem: readlane broadcast cost 640 VALU insts/thread (~+40% issue);
// this body measured ~19us of VALU work in R2. Weights prefetched 4-wide from
// global (L1/L2-hit). BN partials: one coalesced plain store per block.
__global__ __launch_bounds__(256, 8)
void k_convln(const float* __restrict__ x, const float* __restrict__ wT4,
              const float* __restrict__ cb, const float* __restrict__ lg,
              const float* __restrict__ lb, float* __restrict__ h_in,
              float* __restrict__ partials)
{
    __shared__ __align__(16) float xp[64 * 36];   // xp[i][t+2]=x[i][t], zero pad
    __shared__ float red1[64], red2[64];
    __shared__ float wsum[8];
    __shared__ float bcast[2];

    const int b = blockIdx.x, j = threadIdx.x;
    const float* xb = x + (size_t)b * NTC;

#pragma unroll
    for (int r = 0; r < 8; ++r) {
        int idx = j + r * 256;                    // i = idx>>5, t = idx&31
        xp[(idx >> 5) * 36 + (idx & 31) + 2] = xb[idx];
    }
    {
        int i = j >> 2, s = j & 3;
        xp[i * 36 + ((s < 2) ? s : 32 + s)] = 0.f;  // zero pad slots 0,1,34,35
    }
    if (j < 64) { red1[j] = 0.f; red2[j] = 0.f; }
    __syncthreads();

    const int o = j & 63, g = j >> 6;
    const int t0 = g * 8;                         // channel o, t in [t0,t0+8)

    float acc[8];
    {
        float cbv = cb[o];
#pragma unroll
        for (int r = 0; r < 8; ++r) acc[r] = cbv;
    }
    const float4* wrow = (const float4*)wT4 + o;  // stride 64 float4s per i
    const float* xrow = &xp[t0];
    for (int ib = 0; ib < 16; ++ib) {
        float4 w0 = wrow[(ib * 4 + 0) * 64];
        float4 w1 = wrow[(ib * 4 + 1) * 64];
        float4 w2 = wrow[(ib * 4 + 2) * 64];
        float4 w3 = wrow[(ib * 4 + 3) * 64];
#pragma unroll
        for (int k = 0; k < 4; ++k) {
            const int i = ib * 4 + k;
            float4 wv = (k == 0) ? w0 : (k == 1) ? w1 : (k == 2) ? w2 : w3;
            const float* xr = xrow + i * 36;      // wave-uniform, 16B aligned
            float4 q0 = *(const float4*)(xr);
            float4 q1 = *(const float4*)(xr + 4);
            float2 q2 = *(const float2*)(xr + 8);
            float xw[10] = {q0.x,q0.y,q0.z,q0.w,q1.x,q1.y,q1.z,q1.w,q2.x,q2.y};
#pragma unroll
            for (int r = 0; r < 8; ++r)
                acc[r] += xw[r]*wv.x + xw[r+1]*wv.y + xw[r+2]*wv.z;
        }
    }
    // leaky relu + local LN stats
    float s1 = 0.f, s2 = 0.f;
#pragma unroll
    for (int r = 0; r < 8; ++r) {
        float v = acc[r];
        v = (v >= 0.f) ? v : SLOPE_F * v;
        acc[r] = v;
        s1 += v; s2 += v * v;
    }
#pragma unroll
    for (int off = 32; off > 0; off >>= 1) {
        s1 += __shfl_down(s1, off, 64);
        s2 += __shfl_down(s2, off, 64);
    }
    if ((j & 63) == 0) { wsum[j >> 6] = s1; wsum[4 + (j >> 6)] = s2; }
    __syncthreads();
    if (j == 0) {
        float S1 = wsum[0] + wsum[1] + wsum[2] + wsum[3];
        float S2 = wsum[4] + wsum[5] + wsum[6] + wsum[7];
        float mu  = S1 * (1.f / 2048.f);
        float var = S2 * (1.f / 2048.f) - mu * mu;
        bcast[0] = mu;
        bcast[1] = rsqrtf(var + EPS_F);
    }
    __syncthreads();
    const float mu = bcast[0], rs = bcast[1];
    float hs1 = 0.f, hs2 = 0.f;
    float* hb = h_in + (size_t)b * NTC;
#pragma unroll
    for (int r = 0; r < 8; ++r) {
        int t = t0 + r;
        float h = (acc[r] - mu) * rs * lg[o * 32 + t] + lb[o * 32 + t];
        hb[t * 64 + o] = h;                        // coalesced: lanes span o
        hs1 += h; hs2 += h * h;
    }
    atomicAdd(&red1[o], hs1);                      // LDS atomics only
    atomicAdd(&red2[o], hs2);
    __syncthreads();
    float* pb_ = partials + (size_t)b * 128;       // coalesced 512B plain store
    if (j < 64)       pb_[j] = red1[j];
    else if (j < 128) pb_[j] = red2[j - 64];
}

// ---------------- reduce partials -> BN scale/shift ----------------
__global__ __launch_bounds__(256)
void k_bnred(const float* __restrict__ partials, const float* __restrict__ bg,
             const float* __restrict__ bb, float* __restrict__ stats)
{
    const int c = blockIdx.x, j = threadIdx.x;
    float s1 = 0.f, s2 = 0.f;
    for (int b = j; b < NB; b += 256) {
        const float* p = partials + (size_t)b * 128;
        s1 += p[c];
        s2 += p[64 + c];
    }
    __shared__ float r1[4], r2[4];
#pragma unroll
    for (int off = 32; off > 0; off >>= 1) {
        s1 += __shfl_down(s1, off, 64);
        s2 += __shfl_down(s2, off, 64);
    }
    if ((j & 63) == 0) { r1[j >> 6] = s1; r2[j >> 6] = s2; }
    __syncthreads();
    if (j == 0) {
        float S1 = r1[0] + r1[1] + r1[2] + r1[3];
        float S2 = r2[0] + r2[1] + r2[2] + r2[3];
        const float inv_n = 1.f / 65536.f;
        float mu  = S1 * inv_n;
        float var = S2 * inv_n - mu * mu;
        float rs  = rsqrtf(var + EPS_F);
        float sc  = bg[c] * rs;
        stats[128 + c] = sc;
        stats[192 + c] = bb[c] - mu * sc;
    }
}

// ---------------- z = leaky(BN(h)); out = h + z@W0 + tag_b ----------------
__global__ __launch_bounds__(256, 4)
void k_zw0(const float* __restrict__ h_in, const float* __restrict__ stats,
           const float* __restrict__ tw, const float* __restrict__ tb,
           float* __restrict__ z, float* __restrict__ out)
{
    __shared__ float zl[32 * 65];
    __shared__ float hl[32 * 65];
    __shared__ __align__(16) float W[64 * 64];
    const int b = blockIdx.x, j = threadIdx.x;
#pragma unroll
    for (int r = 0; r < 16; ++r) { int idx = j + r * 256; W[idx] = tw[idx]; }
    const int c = j & 63;
    const float sc = stats[128 + c], sh = stats[192 + c];
    const float* hb = h_in + (size_t)b * NTC;
    float* zb = z + (size_t)b * NTC;
#pragma unroll
    for (int r = 0; r < 8; ++r) {
        int idx = j + r * 256;                    // idx = t*64 + c
        int t = idx >> 6;
        float h = hb[idx];
        float zv = h * sc + sh;
        zv = (zv >= 0.f) ? zv : SLOPE_F * zv;
        zb[idx] = zv;
        zl[t * 65 + c] = zv;
        hl[t * 65 + c] = h;
    }
    __syncthreads();
    const int t = j & 31, gq = (j >> 5) * 8;      // outputs (t, gq..gq+7)
    float accm[8];
#pragma unroll
    for (int r = 0; r < 8; ++r)
        accm[r] = tb[gq + r] + hl[t * 65 + gq + r];   // residual + bias
    for (int f = 0; f < 64; ++f) {
        float zv = zl[t * 65 + f];
        const float4* Wr = (const float4*)&W[f * 64 + gq];
        float4 wa = Wr[0], wb = Wr[1];
        accm[0] += zv*wa.x; accm[1] += zv*wa.y; accm[2] += zv*wa.z; accm[3] += zv*wa.w;
        accm[4] += zv*wb.x; accm[5] += zv*wb.y; accm[6] += zv*wb.z; accm[7] += zv*wb.w;
    }
    float* ob = out + (size_t)b * NTC;            // out layout [b][c][t]
#pragma unroll
    for (int r = 0; r < 8; ++r)
        ob[(gq + r) * 32 + t] = accm[r];          // coalesced: lanes span t
}

// ---------------- one propagation hop + fused matmul into out ----------------
__global__ __launch_bounds__(256, 6)
void k_hop(const float* __restrict__ p_in, const int* __restrict__ rowp,
           const int* __restrict__ csrs, const float* __restrict__ csrw,
           const float* __restrict__ tw, float* __restrict__ p_out,
           float* __restrict__ out)
{
    __shared__ float pl[32 * 65];
    __shared__ __align__(16) float W[64 * 64];
    const int d = blockIdx.x, j = threadIdx.x;
#pragma unroll
    for (int r = 0; r < 16; ++r) { int idx = j + r * 256; W[idx] = tw[idx]; }
    const int beg = rowp[d], end = rowp[d + 1];
    float4 a0 = make_float4(0.f,0.f,0.f,0.f), a1 = make_float4(0.f,0.f,0.f,0.f);
    float4 b0 = make_float4(0.f,0.f,0.f,0.f), b1 = make_float4(0.f,0.f,0.f,0.f);
    int e = beg;
    for (; e + 2 <= end; e += 2) {                // 2-edge unroll
        int s0_ = csrs[e],   s1_ = csrs[e+1];
        float w0 = csrw[e],  w1 = csrw[e+1];
        const float4* pb0 = (const float4*)(p_in + (size_t)s0_ * NTC);
        const float4* pb1 = (const float4*)(p_in + (size_t)s1_ * NTC);
        float4 v00 = pb0[j], v01 = pb0[j + 256];
        float4 v10 = pb1[j], v11 = pb1[j + 256];
        a0.x += w0*v00.x; a0.y += w0*v00.y; a0.z += w0*v00.z; a0.w += w0*v00.w;
        a1.x += w0*v01.x; a1.y += w0*v01.y; a1.z += w0*v01.z; a1.w += w0*v01.w;
        b0.x += w1*v10.x; b0.y += w1*v10.y; b0.z += w1*v10.z; b0.w += w1*v10.w;
        b1.x += w1*v11.x; b1.y += w1*v11.y; b1.z += w1*v11.z; b1.w += w1*v11.w;
    }
    if (e < end) {
        int s0_ = csrs[e];
        float w0 = csrw[e];
        const float4* pb0 = (const float4*)(p_in + (size_t)s0_ * NTC);
        float4 v00 = pb0[j], v01 = pb0[j + 256];
        a0.x += w0*v00.x; a0.y += w0*v00.y; a0.z += w0*v00.z; a0.w += w0*v00.w;
        a1.x += w0*v01.x; a1.y += w0*v01.y; a1.z += w0*v01.z; a1.w += w0*v01.w;
    }
    a0.x += b0.x; a0.y += b0.y; a0.z += b0.z; a0.w += b0.w;
    a1.x += b1.x; a1.y += b1.y; a1.z += b1.z; a1.w += b1.w;

    if (p_out) {
        float4* po = (float4*)(p_out + (size_t)d * NTC);
        po[j] = a0;
        po[j + 256] = a1;
    }
    {
        int idx = j * 4;
        int t = idx >> 6, c = idx & 63;
        float* q = &pl[t * 65 + c];
        q[0] = a0.x; q[1] = a0.y; q[2] = a0.z; q[3] = a0.w;
        idx = j * 4 + 1024; t = idx >> 6; c = idx & 63;
        q = &pl[t * 65 + c];
        q[0] = a1.x; q[1] = a1.y; q[2] = a1.z; q[3] = a1.w;
    }
    __syncthreads();
    const int t = j & 31, gq = (j >> 5) * 8;
    float accm[8];
#pragma unroll
    for (int r = 0; r < 8; ++r) accm[r] = 0.f;
    for (int f = 0; f < 64; ++f) {
        float pv = pl[t * 65 + f];
        const float4* Wr = (const float4*)&W[f * 64 + gq];
        float4 wa = Wr[0], wb = Wr[1];
        accm[0] += pv*wa.x; accm[1] += pv*wa.y; accm[2] += pv*wa.z; accm[3] += pv*wa.w;
        accm[4] += pv*wb.x; accm[5] += pv*wb.y; accm[6] += pv*wb.z; accm[7] += pv*wb.w;
    }
    float* ob = out + (size_t)d * NTC;
#pragma unroll
    for (int r = 0; r < 8; ++r)
        ob[(gq + r) * 32 + t] += accm[r];         // block owns node d: safe RMW
}

// ---------------- launch ----------------
// workspace floats (p1 aliases h_in — h_in is dead after k_zw0):
//   [0, 4194304)        h_in [b][t][c]  /  p1 [b][t][c]
//   [4194304, 8388608)  z    [b][t][c]
//   [8388608, +256)     stats (scale[64]@128, shift[64]@192)
//   [8388864, +16384)   wT4
//   [8405248, +262144)  partials [b][128]
//   [8667392, ...)      ints: mode(4) hist(2048) rowp(2052) cur(2048)
//                             csrs(32768) csrw(32768)        (~35 MiB total)
extern "C" void kernel_launch(void* const* d_in, const int* in_sizes, int n_in,
                              void* d_out, int out_size, void* d_ws, size_t ws_size,
                              hipStream_t stream)
{
    const float* x  = (const float*)d_in[0];
    const int*   ei = (const int*)  d_in[1];
    const float* ew = (const float*)d_in[2];
    const float* cw = (const float*)d_in[3];
    const float* cb = (const float*)d_in[4];
    const float* lg = (const float*)d_in[5];
    const float* lb = (const float*)d_in[6];
    const float* bg = (const float*)d_in[7];
    const float* bb = (const float*)d_in[8];
    const float* tw = (const float*)d_in[9];
    const float* tb = (const float*)d_in[10];
    float* out = (float*)d_out;
    float* ws  = (float*)d_ws;

    float* h_in  = ws;
    float* p1    = ws;                 // alias: h_in dead after k_zw0
    float* z     = ws + 4194304;
    float* stats = ws + 8388608;
    float* wT4   = ws + 8388864;
    float* parts = ws + 8405248;
    int*   ib    = (int*)(ws + 8667392);
    int*   mode  = ib;
    int*   hist  = ib + 4;
    int*   rowp  = ib + 2052;
    int*   cur   = ib + 4104;
    int*   csrs  = ib + 6152;
    float* csrw  = (float*)(ib + 38920);

    hipMemsetAsync(ib, 0, 2052 * sizeof(int), stream);   // mode + hist

    k_detect <<<128, 256, 0, stream>>>(ei, mode);
    k_hist   <<<128, 256, 0, stream>>>(ei, mode, hist, cw, wT4);
    k_scan   <<<1,   256, 0, stream>>>(hist, rowp, cur);
    k_scat   <<<128, 256, 0, stream>>>(ei, ew, mode, cur, csrs, csrw);
    k_convln <<<NB,  256, 0, stream>>>(x, wT4, cb, lg, lb, h_in, parts);
    k_bnred  <<<64,  256, 0, stream>>>(parts, bg, bb, stats);
    k_zw0    <<<NB,  256, 0, stream>>>(h_in, stats, tw, tb, z, out);
    k_hop    <<<NB,  256, 0, stream>>>(z,  rowp, csrs, csrw, tw + 4096, p1, out);
    k_hop    <<<NB,  256, 0, stream>>>(p1, rowp, csrs, csrw, tw + 8192, nullptr, out);
}